// Round 2
// baseline (1119.600 us; speedup 1.0000x reference)
//
#include <hip/hip_runtime.h>

#define HID 768
#define NB  128

typedef _Float16 half8  __attribute__((ext_vector_type(8)));
typedef _Float16 half4v __attribute__((ext_vector_type(4)));
typedef float    float4_t __attribute__((ext_vector_type(4)));

// ws layout: fp16 hi plane [48 i-tile16][24 kstep][64 lane][8 halves], then lo plane.
#define OP_TILES (48 * 24)
#define OP_PLANE ((size_t)OP_TILES * 64 * 8)   // 589824 halves = 1.18 MB

// Pre-split operator into fp16 hi/lo, fragment-major (B-operand order).
__global__ __launch_bounds__(256)
void split_op(const float* __restrict__ OP, _Float16* __restrict__ ws)
{
    const int g    = blockIdx.x * 256 + threadIdx.x;
    const int tile = g >> 6, lane = g & 63;
    const int it16 = tile / 24, ks = tile % 24;
    const int i = it16 * 16 + (lane & 15);
    const int k = ks * 32 + (lane >> 4) * 8;
    const float4_t a = *(const float4_t*)(OP + (size_t)i * HID + k);
    const float4_t b = *(const float4_t*)(OP + (size_t)i * HID + k + 4);
    half8 h, l;
#pragma unroll
    for (int e = 0; e < 4; ++e) {
        _Float16 h0 = (_Float16)a[e]; h[e]     = h0; l[e]     = (_Float16)(a[e] - (float)h0);
        _Float16 h1 = (_Float16)b[e]; h[e + 4] = h1; l[e + 4] = (_Float16)(b[e] - (float)h1);
    }
    *(half8*)(ws + (size_t)(tile * 64 + lane) * 8) = h;
    *(half8*)(ws + OP_PLANE + (size_t)(tile * 64 + lane) * 8) = l;
}

// D[b,i] = sum_j op[i,j] * P[j,i],  P = X_b @ op^T (k-reduction).
// Block: (b, 128-wide i-tile). Inner: 3 j-tiles of 256, 24 k-steps of 32.
// A (X) staged through LDS fp16 hi/lo in fragment-major conflict-free layout;
// B (op) fragments loaded straight from L2-resident pre-split ws.
__global__ __launch_bounds__(256, 2)
void diag_quad_kernel(const float* __restrict__ X, const float* __restrict__ OP,
                      const _Float16* __restrict__ opws, float* __restrict__ out)
{
    __shared__ __align__(16) _Float16 Ah[256 * 32];
    __shared__ __align__(16) _Float16 Al[256 * 32];
    __shared__ float Dred[2][128];

    // XCD swizzle: put all 6 i-tile blocks of a batch on one XCD (heuristic: xcd = blockIdx%8)
    const int idx  = blockIdx.x;
    const int xcd  = idx & 7, slot = idx >> 3;   // 96 slots per xcd
    const int b    = xcd * 16 + slot / 6;
    const int it   = slot % 6;
    const int i0   = it * 128;
    const float* Xb = X + (size_t)b * HID * HID;

    const int tid  = threadIdx.x;
    const int lane = tid & 63;
    const int wave = tid >> 6;
    const int wj   = wave & 1;      // j-half (128 rows each)
    const int wi   = wave >> 1;     // i-half (64 each)
    const int m16  = lane & 15;
    const int kg   = lane >> 4;     // 0..3

    // staging coords: 32 rows x 32 cols per pass, 8 passes
    const int srow = tid >> 3;            // 0..31
    const int scol = (tid & 7) * 4;       // 0..28
    const int kgw  = scol >> 3;           // k-chunk of the write
    const int off4 = scol & 7;            // 0 or 4 halves within chunk

    const int fragbase = (kg * 16 + m16) * 8;      // half-index of this lane's chunk
    const int it16base = it * 8 + wi * 4;          // absolute 16-i-tile of tj=0

    float p[4] = {0.f, 0.f, 0.f, 0.f};

    for (int jt = 0; jt < 3; ++jt) {
        const int j0 = jt * 256;
        float4_t acc[8][4];
#pragma unroll
        for (int a = 0; a < 8; ++a)
#pragma unroll
            for (int c = 0; c < 4; ++c) acc[a][c] = (float4_t){0.f, 0.f, 0.f, 0.f};

        for (int ks = 0; ks < 24; ++ks) {
            const int k0 = ks * 32;
            __syncthreads();
            // stage X[j0+r, k0..k0+31] as fp16 hi/lo, fragment-major chunks
#pragma unroll
            for (int pp = 0; pp < 8; ++pp) {
                const int r = pp * 32 + srow;
                const float4_t v = *(const float4_t*)(Xb + (size_t)(j0 + r) * HID + k0 + scol);
                half4v hv, lv;
#pragma unroll
                for (int e = 0; e < 4; ++e) {
                    _Float16 hh = (_Float16)v[e];
                    hv[e] = hh; lv[e] = (_Float16)(v[e] - (float)hh);
                }
                const int ca = ((r >> 4) * 64 + kgw * 16 + (r & 15)) * 8 + off4;
                *(half4v*)&Ah[ca] = hv;
                *(half4v*)&Al[ca] = lv;
            }

            // B fragments straight from ws (L2): lane-linear dwordx4
            half8 bh[4], bl[4];
            const size_t obase = ((size_t)it16base * 24 + ks) * 512 + (size_t)lane * 8;
#pragma unroll
            for (int tj = 0; tj < 4; ++tj) {
                bh[tj] = *(const half8*)(opws + obase + (size_t)tj * 24 * 512);
                bl[tj] = *(const half8*)(opws + OP_PLANE + obase + (size_t)tj * 24 * 512);
            }
            __syncthreads();

#pragma unroll
            for (int ti = 0; ti < 8; ++ti) {
                const int rt = wj * 8 + ti;
                const half8 ah = *(const half8*)&Ah[rt * 512 + fragbase];
                const half8 al = *(const half8*)&Al[rt * 512 + fragbase];
#pragma unroll
                for (int tj = 0; tj < 4; ++tj) {
                    acc[ti][tj] = __builtin_amdgcn_mfma_f32_16x16x32_f16(ah, bh[tj], acc[ti][tj], 0, 0, 0);
                    acc[ti][tj] = __builtin_amdgcn_mfma_f32_16x16x32_f16(al, bh[tj], acc[ti][tj], 0, 0, 0);
                    acc[ti][tj] = __builtin_amdgcn_mfma_f32_16x16x32_f16(ah, bl[tj], acc[ti][tj], 0, 0, 0);
                }
            }
        }

        // fold P against fp32 op: C layout: i = m16 (+tile), j = kg*4+reg (+tile)
#pragma unroll
        for (int tj = 0; tj < 4; ++tj) {
            const int i_abs = i0 + wi * 64 + tj * 16 + m16;
            float s = 0.f;
#pragma unroll
            for (int ti = 0; ti < 8; ++ti) {
                const int jb = j0 + wj * 128 + ti * 16 + kg * 4;
                const float4_t ov = *(const float4_t*)(OP + (size_t)i_abs * HID + jb);
#pragma unroll
                for (int r = 0; r < 4; ++r) s += acc[ti][tj][r] * ov[r];
            }
            p[tj] += s;
        }
    }

    // reduce over kg (lane bits 4,5), then combine the two wj halves
#pragma unroll
    for (int tj = 0; tj < 4; ++tj) {
        p[tj] += __shfl_xor(p[tj], 16);
        p[tj] += __shfl_xor(p[tj], 32);
    }
    if (kg == 0) {
#pragma unroll
        for (int tj = 0; tj < 4; ++tj)
            Dred[wj][wi * 64 + tj * 16 + m16] = p[tj];
    }
    __syncthreads();
    if (tid < 128)
        out[(size_t)b * HID + i0 + tid] = Dred[0][tid] + Dred[1][tid];
}

// in-place row softmax: 128 rows x 768
__global__ __launch_bounds__(768)
void softmax_rows(float* __restrict__ out)
{
    const int row = blockIdx.x;
    const int t = threadIdx.x;
    const int wave = t >> 6, lane = t & 63;
    __shared__ float redm[12];
    __shared__ float reds[12];

    float v = out[(size_t)row * HID + t];

    float m = v;
#pragma unroll
    for (int o = 32; o >= 1; o >>= 1) m = fmaxf(m, __shfl_xor(m, o));
    if (lane == 0) redm[wave] = m;
    __syncthreads();
    if (t == 0) {
        float mm = redm[0];
        for (int w = 1; w < 12; ++w) mm = fmaxf(mm, redm[w]);
        redm[0] = mm;
    }
    __syncthreads();
    m = redm[0];

    const float e = expf(v - m);
    float s = e;
#pragma unroll
    for (int o = 32; o >= 1; o >>= 1) s += __shfl_xor(s, o);
    if (lane == 0) reds[wave] = s;
    __syncthreads();
    if (t == 0) {
        float ss = 0.f;
        for (int w = 0; w < 12; ++w) ss += reds[w];
        reds[0] = ss;
    }
    __syncthreads();
    out[(size_t)row * HID + t] = e / reds[0];
}

extern "C" void kernel_launch(void* const* d_in, const int* in_sizes, int n_in,
                              void* d_out, int out_size, void* d_ws, size_t ws_size,
                              hipStream_t stream)
{
    const float* X  = (const float*)d_in[0];   // [128,768,768] fp32
    const float* OP = (const float*)d_in[1];   // [768,768] fp32
    float* out = (float*)d_out;                // [128,768] fp32
    _Float16* opws = (_Float16*)d_ws;          // 2.36 MB: fp16 hi/lo fragment-major op

    hipLaunchKernelGGL(split_op, dim3(OP_TILES / 4), dim3(256), 0, stream, OP, opws);
    hipLaunchKernelGGL(diag_quad_kernel, dim3(NB * 6), dim3(256), 0, stream, X, OP, opws, out);
    hipLaunchKernelGGL(softmax_rows, dim3(NB), dim3(768), 0, stream, out);
}

// Round 4
// 644.885 us; speedup vs baseline: 1.7361x; 1.7361x over previous
//
#include <hip/hip_runtime.h>

#define HID 768
#define NB  128

typedef _Float16 half8   __attribute__((ext_vector_type(8)));
typedef __fp16   fp16x2  __attribute__((ext_vector_type(2)));
typedef float    float4_t __attribute__((ext_vector_type(4)));

// ws layout: fp16 hi plane [48 i-tile16][24 kstep][64 lane][8 halves], then lo plane.
#define OP_TILES (48 * 24)
#define OP_PLANE ((size_t)OP_TILES * 64 * 8)   // 1.18 MB per plane

// Pre-split operator into fp16 hi/lo, fragment-major (B-operand order).
__global__ __launch_bounds__(256)
void split_op(const float* __restrict__ OP, _Float16* __restrict__ ws)
{
    const int g    = blockIdx.x * 256 + threadIdx.x;
    const int tile = g >> 6, lane = g & 63;
    const int it16 = tile / 24, ks = tile % 24;
    const int i = it16 * 16 + (lane & 15);
    const int k = ks * 32 + (lane >> 4) * 8;
    const float4_t a = *(const float4_t*)(OP + (size_t)i * HID + k);
    const float4_t b = *(const float4_t*)(OP + (size_t)i * HID + k + 4);
    half8 h, l;
#pragma unroll
    for (int e = 0; e < 4; ++e) {
        _Float16 h0 = (_Float16)a[e]; h[e]     = h0; l[e]     = (_Float16)(a[e] - (float)h0);
        _Float16 h1 = (_Float16)b[e]; h[e + 4] = h1; l[e + 4] = (_Float16)(b[e] - (float)h1);
    }
    *(half8*)(ws + (size_t)(tile * 64 + lane) * 8) = h;
    *(half8*)(ws + OP_PLANE + (size_t)(tile * 64 + lane) * 8) = l;
}

__device__ __forceinline__ void convert8(const float4_t a, const float4_t b,
                                         half8& h, half8& l)
{
    // hi = RTZ pack (1 instr / 2 floats); lo = exact residual, RTZ-packed.
    fp16x2 h01 = __builtin_amdgcn_cvt_pkrtz(a[0], a[1]);
    fp16x2 h23 = __builtin_amdgcn_cvt_pkrtz(a[2], a[3]);
    fp16x2 h45 = __builtin_amdgcn_cvt_pkrtz(b[0], b[1]);
    fp16x2 h67 = __builtin_amdgcn_cvt_pkrtz(b[2], b[3]);
    fp16x2 l01 = __builtin_amdgcn_cvt_pkrtz(a[0] - (float)h01[0], a[1] - (float)h01[1]);
    fp16x2 l23 = __builtin_amdgcn_cvt_pkrtz(a[2] - (float)h23[0], a[3] - (float)h23[1]);
    fp16x2 l45 = __builtin_amdgcn_cvt_pkrtz(b[0] - (float)h45[0], b[1] - (float)h45[1]);
    fp16x2 l67 = __builtin_amdgcn_cvt_pkrtz(b[2] - (float)h67[0], b[3] - (float)h67[1]);
    h = (half8){(_Float16)h01[0], (_Float16)h01[1], (_Float16)h23[0], (_Float16)h23[1],
                (_Float16)h45[0], (_Float16)h45[1], (_Float16)h67[0], (_Float16)h67[1]};
    l = (half8){(_Float16)l01[0], (_Float16)l01[1], (_Float16)l23[0], (_Float16)l23[1],
                (_Float16)l45[0], (_Float16)l45[1], (_Float16)l67[0], (_Float16)l67[1]};
}

// D[b,i] = sum_j op[i,j] * P[j,i],  P = X_b @ op^T (k-reduction).
// Block: (b, 128 i) x 128-j tiles; wave: 64j x 64i, acc 4x4 (64 AGPR -> 3 blk/CU).
// A (X) staged in LDS fp16 hi/lo, fragment-major chunks (2-way banks only);
// B (op) fragments loaded straight from L2-resident pre-split ws.
__global__ __launch_bounds__(256, 3)
void diag_quad_kernel(const float* __restrict__ X, const float* __restrict__ OP,
                      const _Float16* __restrict__ opws, float* __restrict__ out)
{
    // chunk (rt,kg,m16): halves offset rt*512 + kg*128 + m16*8  (bytes x2)
    __shared__ __align__(16) _Float16 Ah[4096];
    __shared__ __align__(16) _Float16 Al[4096];
    __shared__ float Dred[2][128];

    // XCD swizzle: 6 i-tile blocks of a batch share an XCD (L2 reuse of X_b)
    const int idx  = blockIdx.x;
    const int xcd  = idx & 7, slot = idx >> 3;
    const int b    = xcd * 16 + slot / 6;
    const int it   = slot % 6;
    const int i0   = it * 128;
    const float* Xb = X + (size_t)b * HID * HID;

    const int tid  = threadIdx.x;
    const int lane = tid & 63;
    const int wave = tid >> 6;
    const int wj   = wave & 1;      // j-half (64 rows)
    const int wi   = wave >> 1;     // i-half (64 cols)
    const int m16  = lane & 15;
    const int kg   = lane >> 4;     // 0..3

    // staging: task t (t=tid, tid+256): row=t>>2 (0..127), kgs=t&3; 32B of k per task
    const int row0 = tid >> 2;
    const int kgs  = tid & 3;
    const int lds0 = (row0 >> 4) * 512 + kgs * 128 + (row0 & 15) * 8;
    const int lds1 = ((row0 + 64) >> 4) * 512 + kgs * 128 + (row0 & 15) * 8;

    const int fragoff  = kg * 128 + m16 * 8;     // + rt*512
    const int it16base = it * 8 + wi * 4;

    float p[4] = {0.f, 0.f, 0.f, 0.f};

    for (int jt = 0; jt < 6; ++jt) {
        const int j0 = jt * 128;
        float4_t acc[4][4];
#pragma unroll
        for (int a = 0; a < 4; ++a)
#pragma unroll
            for (int c = 0; c < 4; ++c) acc[a][c] = (float4_t){0.f, 0.f, 0.f, 0.f};

        for (int ks = 0; ks < 24; ++ks) {
            const int k0 = ks * 32;

            // B fragments straight from ws (L2) — issue early, no LDS dependency
            half8 bh[4], bl[4];
            const size_t obase = ((size_t)it16base * 24 + ks) * 512 + (size_t)lane * 8;
#pragma unroll
            for (int tj = 0; tj < 4; ++tj) {
                bh[tj] = *(const half8*)(opws + obase + (size_t)tj * 24 * 512);
                bl[tj] = *(const half8*)(opws + OP_PLANE + obase + (size_t)tj * 24 * 512);
            }

            // staging global loads (2 tasks x 32B)
            const float* s0 = Xb + (size_t)(j0 + row0) * HID + k0 + kgs * 8;
            const float* s1 = Xb + (size_t)(j0 + row0 + 64) * HID + k0 + kgs * 8;
            const float4_t a0 = *(const float4_t*)(s0);
            const float4_t a1 = *(const float4_t*)(s0 + 4);
            const float4_t b0 = *(const float4_t*)(s1);
            const float4_t b1 = *(const float4_t*)(s1 + 4);
            half8 h0, l0v, h1, l1v;
            convert8(a0, a1, h0, l0v);
            convert8(b0, b1, h1, l1v);

            __syncthreads();   // previous iteration's frag reads complete
            *(half8*)&Ah[lds0] = h0;
            *(half8*)&Al[lds0] = l0v;
            *(half8*)&Ah[lds1] = h1;
            *(half8*)&Al[lds1] = l1v;
            __syncthreads();

#pragma unroll
            for (int ti = 0; ti < 4; ++ti) {
                const int off = (wj * 4 + ti) * 512 + fragoff;
                const half8 ah = *(const half8*)&Ah[off];
                const half8 al = *(const half8*)&Al[off];
#pragma unroll
                for (int tj = 0; tj < 4; ++tj) {
                    acc[ti][tj] = __builtin_amdgcn_mfma_f32_16x16x32_f16(ah, bh[tj], acc[ti][tj], 0, 0, 0);
                    acc[ti][tj] = __builtin_amdgcn_mfma_f32_16x16x32_f16(al, bh[tj], acc[ti][tj], 0, 0, 0);
                    acc[ti][tj] = __builtin_amdgcn_mfma_f32_16x16x32_f16(ah, bl[tj], acc[ti][tj], 0, 0, 0);
                }
            }
        }

        // fold P against fp32 op: C layout: i = m16 (+tiles), j = kg*4 + reg (+tiles)
#pragma unroll
        for (int tj = 0; tj < 4; ++tj) {
            const int i_abs = i0 + wi * 64 + tj * 16 + m16;
            float s = 0.f;
#pragma unroll
            for (int ti = 0; ti < 4; ++ti) {
                const int jb = j0 + wj * 64 + ti * 16 + kg * 4;
                const float4_t ov = *(const float4_t*)(OP + (size_t)i_abs * HID + jb);
#pragma unroll
                for (int r = 0; r < 4; ++r) s += acc[ti][tj][r] * ov[r];
            }
            p[tj] += s;
        }
    }

    // reduce over kg (lane bits 4,5), then combine the two wj halves
#pragma unroll
    for (int tj = 0; tj < 4; ++tj) {
        p[tj] += __shfl_xor(p[tj], 16);
        p[tj] += __shfl_xor(p[tj], 32);
    }
    if (kg == 0) {
#pragma unroll
        for (int tj = 0; tj < 4; ++tj)
            Dred[wj][wi * 64 + tj * 16 + m16] = p[tj];
    }
    __syncthreads();
    if (tid < 128)
        out[(size_t)b * HID + i0 + tid] = Dred[0][tid] + Dred[1][tid];
}

// in-place row softmax: 128 rows x 768
__global__ __launch_bounds__(768)
void softmax_rows(float* __restrict__ out)
{
    const int row = blockIdx.x;
    const int t = threadIdx.x;
    const int wave = t >> 6, lane = t & 63;
    __shared__ float redm[12];
    __shared__ float reds[12];

    float v = out[(size_t)row * HID + t];

    float m = v;
#pragma unroll
    for (int o = 32; o >= 1; o >>= 1) m = fmaxf(m, __shfl_xor(m, o));
    if (lane == 0) redm[wave] = m;
    __syncthreads();
    if (t == 0) {
        float mm = redm[0];
        for (int w = 1; w < 12; ++w) mm = fmaxf(mm, redm[w]);
        redm[0] = mm;
    }
    __syncthreads();
    m = redm[0];

    const float e = expf(v - m);
    float s = e;
#pragma unroll
    for (int o = 32; o >= 1; o >>= 1) s += __shfl_xor(s, o);
    if (lane == 0) reds[wave] = s;
    __syncthreads();
    if (t == 0) {
        float ss = 0.f;
        for (int w = 0; w < 12; ++w) ss += reds[w];
        reds[0] = ss;
    }
    __syncthreads();
    out[(size_t)row * HID + t] = e / reds[0];
}

extern "C" void kernel_launch(void* const* d_in, const int* in_sizes, int n_in,
                              void* d_out, int out_size, void* d_ws, size_t ws_size,
                              hipStream_t stream)
{
    const float* X  = (const float*)d_in[0];   // [128,768,768] fp32
    const float* OP = (const float*)d_in[1];   // [768,768] fp32
    float* out = (float*)d_out;                // [128,768] fp32
    _Float16* opws = (_Float16*)d_ws;          // 2.36 MB pre-split op

    hipLaunchKernelGGL(split_op, dim3(OP_TILES / 4), dim3(256), 0, stream, OP, opws);
    hipLaunchKernelGGL(diag_quad_kernel, dim3(NB * 6), dim3(256), 0, stream, X, OP, opws, out);
    hipLaunchKernelGGL(softmax_rows, dim3(NB), dim3(768), 0, stream, out);
}